// Round 8
// baseline (51.223 us; speedup 1.0000x reference)
//
#include <hip/hip_runtime.h>

#define NNODE 8
#define FDIM 512
#define HDIM 256
#define ODIM 128
#define BATCH 8192
#define SPB 16
#define NBLK (BATCH / SPB)      // 512

#define OCH 16                  // o-columns per build block
#define QCH (ODIM / OCH)        // 8
#define NGR 16                  // r-groups per build block
#define CHK (HDIM / NGR)        // 16
#define NBUILD (NNODE * QCH)    // 64 build blocks

// ws float offsets
#define OFF_TAU  0                                   // tau_sorted[8][256]
#define OFF_TAB  (NNODE * HDIM)                      // 2048: float2 table [8][257][128]
#define OFF_FLAG (OFF_TAB + NNODE * 257 * ODIM * 2)  // 528384

__global__ __launch_bounds__(256, 2) void gnn_one(
    const float* __restrict__ latent, const float* __restrict__ nf,
    const float* __restrict__ ea, const float* __restrict__ b1,
    const float* __restrict__ W1, const float* __restrict__ W2,
    const float* __restrict__ b2, float* __restrict__ ws,
    float* __restrict__ out)
{
    const int tid = threadIdx.x;
    const int b = blockIdx.x;
    const int bs = b * SPB;

    // shared by all blocks
    __shared__ float A_s[64], dinv_s[NNODE], m_s[NNODE];
    __shared__ float lat_s[SPB][NNODE];
    __shared__ float cc_s[SPB][NNODE];
    __shared__ int   rr_s[SPB][NNODE];
    __shared__ float tau_m[NNODE][HDIM];      // 8 KiB
    // build-only (blocks 0..63)
    __shared__ float v_s[FDIM];               // 2 KiB
    __shared__ float P_s[HDIM], k_s[HDIM], tau_b[HDIM];
    __shared__ int   hs_s[HDIM];
    __shared__ float pe_s[HDIM], ke_s[HDIM], bp_s[HDIM], bk_s[HDIM];
    __shared__ float cta[NGR][OCH], ctb[NGR][OCH], eta[NGR][OCH], etb[NGR][OCH];

    unsigned int* flag = (unsigned int*)(ws + OFF_FLAG);

    // ---- latent loads (threads 128..255), overlaps A_hat setup ----
    if (tid >= 128) {
        int u = tid - 128;
        lat_s[u >> 3][u & 7] = latent[(size_t)(bs + (u >> 3)) * FDIM + (u & 7)];
    }

    // ---- A_hat in parallel (every block; trivial) ----
    if (tid < 64) {
        int i = tid >> 3, qn = tid & 7;
        float a = (i == qn) ? 1.f : 0.f;
        if (i != qn) a += ea[qn * 7 + i - (i > qn ? 1 : 0)];   // edge src=qn, dst=i
        A_s[tid] = a;
    }
    __syncthreads();
    if (tid < NNODE) {
        float d = 0.f;
#pragma unroll
        for (int qq = 0; qq < NNODE; qq++) d += A_s[tid * 8 + qq];
        dinv_s[tid] = d > 0.f ? 1.0f / sqrtf(d) : 0.f;
    }
    __syncthreads();
    if (tid < 64) {
        int i = tid >> 3, qn = tid & 7;
        A_s[tid] = dinv_s[i] * A_s[tid] * dinv_s[qn];
    }
    __syncthreads();
    if (tid < NNODE) {
        float mm = 0.f;
#pragma unroll
        for (int i = 0; i < NNODE; i++) mm += A_s[i * 8 + tid];
        m_s[tid] = mm * 0.125f;
    }

    // ---- softmax + c[s][i] (threads 0..127), pre-spin ----
    float c_keep = 0.f;
    if (tid < SPB * NNODE) {
        int s = tid >> 3, i = tid & 7;
        float mx = -1e30f;
#pragma unroll
        for (int qq = 0; qq < NNODE; qq++) mx = fmaxf(mx, lat_s[s][qq]);
        float sum = 0.f, acc = 0.f;
#pragma unroll
        for (int qq = 0; qq < NNODE; qq++) {
            float e = expf(lat_s[s][qq] - mx);
            sum += e;
            acc = fmaf(A_s[i * NNODE + qq], e, acc);
        }
        c_keep = acc / sum;
        cc_s[s][i] = c_keep;
    }

    // =================== BUILD (blocks 0..63) ===================
    if (b < NBUILD) {
        const int j = b >> 3;
        const int q = b & (QCH - 1);
        const int obase = q * OCH;

        // v_j[f] = sum_n Ahat[j][n] * nf[n][f]   (2 elems/thread)
        {
            float aj[NNODE];
#pragma unroll
            for (int n = 0; n < NNODE; n++) aj[n] = A_s[j * 8 + n];
#pragma unroll
            for (int u = 0; u < 2; u++) {
                int f = tid + u * 256;
                float v = 0.f;
#pragma unroll
                for (int n = 0; n < NNODE; n++) v = fmaf(aj[n], nf[n * FDIM + f], v);
                v_s[f] = v;
            }
        }
        __syncthreads();   // v_s, m_s ready

        // two dots over f: P (with v) and s1, shared W1 load; h = tid
        {
            const float* Wc = W1 + tid;
            float pp = 0.f, ss = 0.f;
#pragma unroll 8
            for (int f = 0; f < FDIM; f++) {
                float w = Wc[(size_t)f * HDIM];
                pp = fmaf(v_s[f], w, pp);
                ss += w;
            }
            float P = b1[tid] + pp;
            float kap = 0.1f * ss;
            float tau = (kap != 0.f) ? (-P / kap) : __builtin_inff();
            P_s[tid] = P;
            k_s[tid] = kap;
            tau_b[tid] = tau;
            float mj = m_s[j];
            bp_s[tid] = mj * ((kap < 0.f || (kap == 0.f && P > 0.f)) ? P : 0.f);
            bk_s[tid] = mj * ((kap < 0.f) ? kap : 0.f);
        }
        __syncthreads();

        // rank sort (full loop per thread)
        {
            float th = tau_b[tid];
            int r = 0;
            for (int k = 0; k < HDIM; k++) {
                float tk = tau_b[k];
                r += (tk < th) || (tk == th && k < tid);
            }
            hs_s[r] = tid;
            if (q == 0) ws[OFF_TAU + j * HDIM + r] = th;
        }
        __syncthreads();
        {
            int h2 = hs_s[tid];
            float kk = k_s[h2], pp = P_s[h2];
            float sgn = (kk > 0.f) ? 1.f : ((kk < 0.f) ? -1.f : 0.f);
            float mj = m_s[j];
            pe_s[tid] = mj * sgn * pp;
            ke_s[tid] = mj * sgn * kk;
        }
        __syncthreads();

        // tab pass 1: base partials + event chunk totals
        const int oc = tid & (OCH - 1);
        const int rr = tid >> 4;     // 0..15
        {
            float ba = 0.f, bb = 0.f, sa = 0.f, sb = 0.f;
#pragma unroll
            for (int k = 0; k < CHK; k++) {
                int h = rr * CHK + k;
                float wb = W2[h * ODIM + obase + oc];
                ba = fmaf(bp_s[h], wb, ba);
                bb = fmaf(bk_s[h], wb, bb);
                float we = W2[hs_s[h] * ODIM + obase + oc];   // h doubles as r
                sa = fmaf(pe_s[h], we, sa);
                sb = fmaf(ke_s[h], we, sb);
            }
            cta[rr][oc] = ba; ctb[rr][oc] = bb;
            eta[rr][oc] = sa; etb[rr][oc] = sb;
        }
        __syncthreads();

        float2* TAB = (float2*)(ws + OFF_TAB);

        // owners: base total + row 0 + exclusive scan of 16 chunks
        if (tid < OCH) {
            const int o = tid;
            float accA = 0.f, accB = 0.f;
#pragma unroll
            for (int g = 0; g < NGR; g++) { accA += cta[g][o]; accB += ctb[g][o]; }
            if (j == 0) accA += b2[obase + o];
            TAB[(size_t)(j * 257) * ODIM + obase + o] = make_float2(accA, accB);
#pragma unroll
            for (int g = 0; g < NGR; g++) {
                float ta = eta[g][o], tb = etb[g][o];
                eta[g][o] = accA; etb[g][o] = accB;
                accA += ta; accB += tb;
            }
        }
        __syncthreads();

        // pass 2: recompute with offset, write rows r+1
        {
            float ra = eta[rr][oc], rb = etb[rr][oc];
#pragma unroll
            for (int k = 0; k < CHK; k++) {
                int r = rr * CHK + k;
                float we = W2[hs_s[r] * ODIM + obase + oc];
                ra = fmaf(pe_s[r], we, ra);
                rb = fmaf(ke_s[r], we, rb);
                TAB[(size_t)(j * 257 + r + 1) * ODIM + obase + oc] = make_float2(ra, rb);
            }
        }
        __syncthreads();   // drains all vmem stores of the block
        if (tid == 0)
            __hip_atomic_fetch_add(flag, 1u, __ATOMIC_RELEASE, __HIP_MEMORY_SCOPE_AGENT);
    }

    // =================== WAIT for table ===================
    if (tid == 0) {
        while (__hip_atomic_fetch_add(flag, 0u, __ATOMIC_RELAXED,
                                      __HIP_MEMORY_SCOPE_AGENT) < (unsigned)NBUILD)
            __builtin_amdgcn_s_sleep(8);
        __threadfence();   // agent-scope acquire: invalidate L1/L2
    }
    __syncthreads();

    // =================== MAIN lookup ===================
    for (int k = tid; k < NNODE * HDIM; k += 256)
        ((float*)tau_m)[k] = ws[OFF_TAU + k];
    __syncthreads();

    if (tid < SPB * NNODE) {   // binary search with register-held c
        int s = tid >> 3, i = tid & 7;
        float c = c_keep;
        int lo = 0, hi = HDIM;
        while (lo < hi) {
            int mid = (lo + hi) >> 1;
            if (tau_m[i][mid] < c) lo = mid + 1; else hi = mid;
        }
        rr_s[s][i] = lo;
    }
    __syncthreads();

    const int o = tid & (ODIM - 1);
    const int sh = tid >> 7;                 // 0 or 1
    const float2* TAB = (const float2*)(ws + OFF_TAB);

#pragma unroll 2
    for (int s = sh; s < SPB; s += 2) {
        float acc = 0.f;
#pragma unroll
        for (int jj = 0; jj < NNODE; jj++) {
            int r = rr_s[s][jj];
            float c = cc_s[s][jj];
            float2 ab = TAB[(size_t)(jj * 257 + r) * ODIM + o];
            acc += fmaf(c, ab.y, ab.x);
        }
        out[(size_t)(bs + s) * ODIM + o] = acc;
    }
}

extern "C" void kernel_launch(void* const* d_in, const int* in_sizes, int n_in,
                              void* d_out, int out_size, void* d_ws, size_t ws_size,
                              hipStream_t stream) {
    const float* latent = (const float*)d_in[0];
    const float* nf     = (const float*)d_in[1];
    const float* ea     = (const float*)d_in[2];
    const float* W1     = (const float*)d_in[3];
    const float* b1     = (const float*)d_in[4];
    const float* W2     = (const float*)d_in[5];
    const float* b2     = (const float*)d_in[6];
    float* out = (float*)d_out;
    float* ws  = (float*)d_ws;

    // zero the flag (4 bytes) — graph memset node, capturable
    hipMemsetAsync((char*)d_ws + (size_t)OFF_FLAG * sizeof(float), 0, 4, stream);
    hipLaunchKernelGGL(gnn_one, dim3(NBLK), dim3(256), 0, stream,
                       latent, nf, ea, b1, W1, W2, b2, ws, out);
}

// Round 9
// 47.331 us; speedup vs baseline: 1.0822x; 1.0822x over previous
//
#include <hip/hip_runtime.h>

#define NNODE 8
#define FDIM 512
#define HDIM 256
#define ODIM 128
#define BATCH 8192
#define SPB 16
#define NBLK (BATCH / SPB)      // 512

#define OCH 16                  // o-columns per build block
#define QCH (ODIM / OCH)        // 8
#define NGR 16                  // r-groups per build block
#define CHK (HDIM / NGR)        // 16
#define NBUILD (NNODE * QCH)    // 64 build blocks

// ws float offsets
#define OFF_TAU  0                                   // tau_sorted[8][256]
#define OFF_TAB  (NNODE * HDIM)                      // 2048: float2 table [8][257][128]
#define OFF_FLAG (OFF_TAB + NNODE * 257 * ODIM * 2)  // 528384

__global__ __launch_bounds__(256, 2) void gnn_one(
    const float* __restrict__ latent, const float* __restrict__ nf,
    const float* __restrict__ ea, const float* __restrict__ b1,
    const float* __restrict__ W1, const float* __restrict__ W2,
    const float* __restrict__ b2, float* __restrict__ ws,
    float* __restrict__ out)
{
    const int tid = threadIdx.x;
    const int b = blockIdx.x;
    const int bs = b * SPB;

    // shared by all blocks
    __shared__ float A_s[64], dinv_s[NNODE], m_s[NNODE];
    __shared__ float lat_s[SPB][NNODE];
    __shared__ float cc_s[SPB][NNODE];
    __shared__ int   rr_s[SPB][NNODE];
    __shared__ float tau_m[NNODE][HDIM];      // 8 KiB
    // build-only (blocks 0..63)
    __shared__ float v_s[FDIM];               // 2 KiB
    __shared__ float P_s[HDIM], k_s[HDIM], tau_b[HDIM];
    __shared__ int   hs_s[HDIM];
    __shared__ float pe_s[HDIM], ke_s[HDIM], bp_s[HDIM], bk_s[HDIM];
    __shared__ float cta[NGR][OCH], ctb[NGR][OCH], eta[NGR][OCH], etb[NGR][OCH];

    unsigned int* flag = (unsigned int*)(ws + OFF_FLAG);

    // ---- latent loads (threads 128..255), overlaps A_hat setup ----
    if (tid >= 128) {
        int u = tid - 128;
        lat_s[u >> 3][u & 7] = latent[(size_t)(bs + (u >> 3)) * FDIM + (u & 7)];
    }

    // ---- A_hat in parallel (every block; trivial) ----
    if (tid < 64) {
        int i = tid >> 3, qn = tid & 7;
        float a = (i == qn) ? 1.f : 0.f;
        if (i != qn) a += ea[qn * 7 + i - (i > qn ? 1 : 0)];   // edge src=qn, dst=i
        A_s[tid] = a;
    }
    __syncthreads();
    if (tid < NNODE) {
        float d = 0.f;
#pragma unroll
        for (int qq = 0; qq < NNODE; qq++) d += A_s[tid * 8 + qq];
        dinv_s[tid] = d > 0.f ? 1.0f / sqrtf(d) : 0.f;
    }
    __syncthreads();
    if (tid < 64) {
        int i = tid >> 3, qn = tid & 7;
        A_s[tid] = dinv_s[i] * A_s[tid] * dinv_s[qn];
    }
    __syncthreads();
    if (tid < NNODE) {
        float mm = 0.f;
#pragma unroll
        for (int i = 0; i < NNODE; i++) mm += A_s[i * 8 + tid];
        m_s[tid] = mm * 0.125f;
    }

    // ---- softmax + c[s][i] (threads 0..127), pre-spin ----
    float c_keep = 0.f;
    if (tid < SPB * NNODE) {
        int s = tid >> 3, i = tid & 7;
        float mx = -1e30f;
#pragma unroll
        for (int qq = 0; qq < NNODE; qq++) mx = fmaxf(mx, lat_s[s][qq]);
        float sum = 0.f, acc = 0.f;
#pragma unroll
        for (int qq = 0; qq < NNODE; qq++) {
            float e = expf(lat_s[s][qq] - mx);
            sum += e;
            acc = fmaf(A_s[i * NNODE + qq], e, acc);
        }
        c_keep = acc / sum;
        cc_s[s][i] = c_keep;
    }

    // =================== BUILD (blocks 0..63) ===================
    if (b < NBUILD) {
        const int j = b >> 3;
        const int q = b & (QCH - 1);
        const int obase = q * OCH;

        // v_j[f] = sum_n Ahat[j][n] * nf[n][f]   (2 elems/thread)
        {
            float aj[NNODE];
#pragma unroll
            for (int n = 0; n < NNODE; n++) aj[n] = A_s[j * 8 + n];
#pragma unroll
            for (int u = 0; u < 2; u++) {
                int f = tid + u * 256;
                float v = 0.f;
#pragma unroll
                for (int n = 0; n < NNODE; n++) v = fmaf(aj[n], nf[n * FDIM + f], v);
                v_s[f] = v;
            }
        }
        __syncthreads();   // v_s, m_s ready

        // two dots over f: P (with v) and s1, shared W1 load; h = tid
        {
            const float* Wc = W1 + tid;
            float pp = 0.f, ss = 0.f;
#pragma unroll 8
            for (int f = 0; f < FDIM; f++) {
                float w = Wc[(size_t)f * HDIM];
                pp = fmaf(v_s[f], w, pp);
                ss += w;
            }
            float P = b1[tid] + pp;
            float kap = 0.1f * ss;
            float tau = (kap != 0.f) ? (-P / kap) : __builtin_inff();
            P_s[tid] = P;
            k_s[tid] = kap;
            tau_b[tid] = tau;
            float mj = m_s[j];
            bp_s[tid] = mj * ((kap < 0.f || (kap == 0.f && P > 0.f)) ? P : 0.f);
            bk_s[tid] = mj * ((kap < 0.f) ? kap : 0.f);
        }
        __syncthreads();

        // rank sort (full loop per thread)
        {
            float th = tau_b[tid];
            int r = 0;
            for (int k = 0; k < HDIM; k++) {
                float tk = tau_b[k];
                r += (tk < th) || (tk == th && k < tid);
            }
            hs_s[r] = tid;
            if (q == 0) ws[OFF_TAU + j * HDIM + r] = th;
        }
        __syncthreads();
        {
            int h2 = hs_s[tid];
            float kk = k_s[h2], pp = P_s[h2];
            float sgn = (kk > 0.f) ? 1.f : ((kk < 0.f) ? -1.f : 0.f);
            float mj = m_s[j];
            pe_s[tid] = mj * sgn * pp;
            ke_s[tid] = mj * sgn * kk;
        }
        __syncthreads();

        // tab pass 1: base partials + event chunk totals
        const int oc = tid & (OCH - 1);
        const int rr = tid >> 4;     // 0..15
        {
            float ba = 0.f, bb = 0.f, sa = 0.f, sb = 0.f;
#pragma unroll
            for (int k = 0; k < CHK; k++) {
                int h = rr * CHK + k;
                float wb = W2[h * ODIM + obase + oc];
                ba = fmaf(bp_s[h], wb, ba);
                bb = fmaf(bk_s[h], wb, bb);
                float we = W2[hs_s[h] * ODIM + obase + oc];   // h doubles as r
                sa = fmaf(pe_s[h], we, sa);
                sb = fmaf(ke_s[h], we, sb);
            }
            cta[rr][oc] = ba; ctb[rr][oc] = bb;
            eta[rr][oc] = sa; etb[rr][oc] = sb;
        }
        __syncthreads();

        float2* TAB = (float2*)(ws + OFF_TAB);

        // owners: base total + row 0 + exclusive scan of 16 chunks
        if (tid < OCH) {
            const int o = tid;
            float accA = 0.f, accB = 0.f;
#pragma unroll
            for (int g = 0; g < NGR; g++) { accA += cta[g][o]; accB += ctb[g][o]; }
            if (j == 0) accA += b2[obase + o];
            TAB[(size_t)(j * 257) * ODIM + obase + o] = make_float2(accA, accB);
#pragma unroll
            for (int g = 0; g < NGR; g++) {
                float ta = eta[g][o], tb = etb[g][o];
                eta[g][o] = accA; etb[g][o] = accB;
                accA += ta; accB += tb;
            }
        }
        __syncthreads();

        // pass 2: recompute with offset, write rows r+1
        {
            float ra = eta[rr][oc], rb = etb[rr][oc];
#pragma unroll
            for (int k = 0; k < CHK; k++) {
                int r = rr * CHK + k;
                float we = W2[hs_s[r] * ODIM + obase + oc];
                ra = fmaf(pe_s[r], we, ra);
                rb = fmaf(ke_s[r], we, rb);
                TAB[(size_t)(j * 257 + r + 1) * ODIM + obase + oc] = make_float2(ra, rb);
            }
        }
        __syncthreads();   // block's table stores issued
        if (tid == 0)
            __hip_atomic_fetch_add(flag, 1u, __ATOMIC_RELEASE, __HIP_MEMORY_SCOPE_AGENT);
    }

    // =================== WAIT for table (load-only poll) ===================
    if (tid == 0) {
        while (__hip_atomic_load(flag, __ATOMIC_RELAXED,
                                 __HIP_MEMORY_SCOPE_AGENT) < (unsigned)NBUILD)
            __builtin_amdgcn_s_sleep(16);
        // one acquire load to order subsequent table reads
        (void)__hip_atomic_load(flag, __ATOMIC_ACQUIRE, __HIP_MEMORY_SCOPE_AGENT);
    }
    __syncthreads();

    // =================== MAIN lookup ===================
    for (int k = tid; k < NNODE * HDIM; k += 256)
        ((float*)tau_m)[k] = ws[OFF_TAU + k];
    __syncthreads();

    if (tid < SPB * NNODE) {   // binary search with register-held c
        int s = tid >> 3, i = tid & 7;
        float c = c_keep;
        int lo = 0, hi = HDIM;
        while (lo < hi) {
            int mid = (lo + hi) >> 1;
            if (tau_m[i][mid] < c) lo = mid + 1; else hi = mid;
        }
        rr_s[s][i] = lo;
    }
    __syncthreads();

    const int o = tid & (ODIM - 1);
    const int sh = tid >> 7;                 // 0 or 1
    const float2* TAB = (const float2*)(ws + OFF_TAB);

#pragma unroll 2
    for (int s = sh; s < SPB; s += 2) {
        float acc = 0.f;
#pragma unroll
        for (int jj = 0; jj < NNODE; jj++) {
            int r = rr_s[s][jj];
            float c = cc_s[s][jj];
            float2 ab = TAB[(size_t)(jj * 257 + r) * ODIM + o];
            acc += fmaf(c, ab.y, ab.x);
        }
        out[(size_t)(bs + s) * ODIM + o] = acc;
    }
}

extern "C" void kernel_launch(void* const* d_in, const int* in_sizes, int n_in,
                              void* d_out, int out_size, void* d_ws, size_t ws_size,
                              hipStream_t stream) {
    const float* latent = (const float*)d_in[0];
    const float* nf     = (const float*)d_in[1];
    const float* ea     = (const float*)d_in[2];
    const float* W1     = (const float*)d_in[3];
    const float* b1     = (const float*)d_in[4];
    const float* W2     = (const float*)d_in[5];
    const float* b2     = (const float*)d_in[6];
    float* out = (float*)d_out;
    float* ws  = (float*)d_ws;

    // zero the flag (4 bytes) — graph memset node, capturable
    hipMemsetAsync((char*)d_ws + (size_t)OFF_FLAG * sizeof(float), 0, 4, stream);
    hipLaunchKernelGGL(gnn_one, dim3(NBLK), dim3(256), 0, stream,
                       latent, nf, ea, b1, W1, W2, b2, ws, out);
}

// Round 10
// 25.659 us; speedup vs baseline: 1.9963x; 1.8446x over previous
//
#include <hip/hip_runtime.h>

#define NNODE 8
#define FDIM 512
#define HDIM 256
#define ODIM 128
#define BATCH 8192
#define SPB 16
#define NBLK (BATCH / SPB)      // 512

#define OCH 16                  // o-columns per build block
#define QCH (ODIM / OCH)        // 8
#define NGR 64                  // r-groups per build block (1024 thr)
#define CHK (HDIM / NGR)        // 4

// ws float offsets
#define OFF_TAU  0                           // tau_sorted[8][256]
#define OFF_AHAT (NNODE * HDIM)              // 2048: Ahat[64]
#define OFF_TAB  (OFF_AHAT + 128)            // 2176: float2 table [8][257][128]

// ============ K1: build, 64 blocks x 1024 threads ============
__global__ __launch_bounds__(1024) void gnn_build(
    const float* __restrict__ nf, const float* __restrict__ W1,
    const float* __restrict__ ea, const float* __restrict__ b1,
    const float* __restrict__ W2, const float* __restrict__ b2,
    float* __restrict__ ws)
{
    const int tid = threadIdx.x;
    const int j = blockIdx.x >> 3;           // node 0..7
    const int q = blockIdx.x & (QCH - 1);    // o-chunk 0..7
    const int obase = q * OCH;

    __shared__ float v_s[FDIM];              // 2 KiB
    __shared__ float pp_s[4][HDIM];          // 4 KiB
    __shared__ float ss_s[4][HDIM];          // 4 KiB
    __shared__ float A_s[64], dinv_s[NNODE], m_s[NNODE];
    __shared__ float P_s[HDIM], k_s[HDIM], tau_s[HDIM];
    __shared__ int   hs_s[HDIM];
    __shared__ int   rp_s[4][HDIM];          // 4 KiB
    __shared__ float pe_s[HDIM], ke_s[HDIM], bp_s[HDIM], bk_s[HDIM];
    __shared__ float cta[NGR][OCH], ctb[NGR][OCH], eta[NGR][OCH], etb[NGR][OCH]; // 16 KiB

    // ---- A_hat in parallel ----
    if (tid < 64) {
        int i = tid >> 3, qn = tid & 7;
        float a = (i == qn) ? 1.f : 0.f;
        if (i != qn) a += ea[qn * 7 + i - (i > qn ? 1 : 0)];   // edge src=qn, dst=i
        A_s[tid] = a;
    }
    __syncthreads();
    if (tid < NNODE) {
        float d = 0.f;
#pragma unroll
        for (int qq = 0; qq < NNODE; qq++) d += A_s[tid * 8 + qq];
        dinv_s[tid] = d > 0.f ? 1.0f / sqrtf(d) : 0.f;
    }
    __syncthreads();
    if (tid < 64) {
        int i = tid >> 3, qn = tid & 7;
        A_s[tid] = dinv_s[i] * A_s[tid] * dinv_s[qn];
    }
    __syncthreads();
    if (tid < NNODE) {
        float mm = 0.f;
#pragma unroll
        for (int i = 0; i < NNODE; i++) mm += A_s[i * 8 + tid];
        m_s[tid] = mm * 0.125f;
    }
    // ---- v_j[f] (threads 0..511) ----
    if (tid < FDIM) {
        float v = 0.f;
#pragma unroll
        for (int n = 0; n < NNODE; n++) v = fmaf(A_s[j * 8 + n], nf[n * FDIM + tid], v);
        v_s[tid] = v;
    }
    __syncthreads();

    // ---- dots over f, 4-way split: h = tid&255, g = tid>>8 ----
    {
        const int h = tid & 255;
        const int g = tid >> 8;
        const float* Wp = W1 + (g * 128) * HDIM + h;
        const float* vp = v_s + g * 128;
        float pp = 0.f, ss = 0.f;
#pragma unroll 16
        for (int ff = 0; ff < 128; ff++) {
            float w = Wp[(size_t)ff * HDIM];
            pp = fmaf(vp[ff], w, pp);
            ss += w;
        }
        pp_s[g][h] = pp;
        ss_s[g][h] = ss;
    }
    __syncthreads();

    // ---- prep: P, kappa, tau, base coeffs (threads 0..255) ----
    if (tid < HDIM) {
        float P = b1[tid] + ((pp_s[0][tid] + pp_s[1][tid]) + (pp_s[2][tid] + pp_s[3][tid]));
        float s1 = ((ss_s[0][tid] + ss_s[1][tid]) + (ss_s[2][tid] + ss_s[3][tid]));
        float kap = 0.1f * s1;
        float tau = (kap != 0.f) ? (-P / kap) : __builtin_inff();
        P_s[tid] = P;
        k_s[tid] = kap;
        tau_s[tid] = tau;
        float mj = m_s[j];
        bp_s[tid] = mj * ((kap < 0.f || (kap == 0.f && P > 0.f)) ? P : 0.f);
        bk_s[tid] = mj * ((kap < 0.f) ? kap : 0.f);
    }
    __syncthreads();

    // ---- rank sort, 4-way parallel ----
    {
        const int h = tid & 255, kq = tid >> 8;
        float th = tau_s[h];
        int r = 0;
        for (int k = kq * 64; k < kq * 64 + 64; k++) {
            float tk = tau_s[k];
            r += (tk < th) || (tk == th && k < h);
        }
        rp_s[kq][h] = r;
    }
    __syncthreads();
    if (tid < HDIM) {
        int r = rp_s[0][tid] + rp_s[1][tid] + rp_s[2][tid] + rp_s[3][tid];
        hs_s[r] = tid;
        if (q == 0) ws[OFF_TAU + j * HDIM + r] = tau_s[tid];
    }
    if (blockIdx.x == 0 && tid >= 256 && tid < 320)
        ws[OFF_AHAT + tid - 256] = A_s[tid - 256];
    __syncthreads();
    if (tid < HDIM) {
        int h2 = hs_s[tid];
        float kk = k_s[h2], pp = P_s[h2];
        float sgn = (kk > 0.f) ? 1.f : ((kk < 0.f) ? -1.f : 0.f);
        float mj = m_s[j];
        pe_s[tid] = mj * sgn * pp;
        ke_s[tid] = mj * sgn * kk;
    }
    __syncthreads();

    // ---- tab pass 1: base partials + event chunk totals ----
    const int oc = tid & (OCH - 1);
    const int rr = tid >> 4;     // 0..63
    {
        float ba = 0.f, bb = 0.f, sa = 0.f, sb = 0.f;
#pragma unroll
        for (int k = 0; k < CHK; k++) {
            int h = rr * CHK + k;
            float wb = W2[h * ODIM + obase + oc];
            ba = fmaf(bp_s[h], wb, ba);
            bb = fmaf(bk_s[h], wb, bb);
            float we = W2[hs_s[h] * ODIM + obase + oc];   // h doubles as r
            sa = fmaf(pe_s[h], we, sa);
            sb = fmaf(ke_s[h], we, sb);
        }
        cta[rr][oc] = ba; ctb[rr][oc] = bb;
        eta[rr][oc] = sa; etb[rr][oc] = sb;
    }
    __syncthreads();

    float2* TAB = (float2*)(ws + OFF_TAB);

    // ---- owners: base total + row 0 + exclusive scan of 64 chunks ----
    if (tid < OCH) {
        const int o = tid;
        float accA = 0.f, accB = 0.f;
#pragma unroll
        for (int g = 0; g < NGR; g++) { accA += cta[g][o]; accB += ctb[g][o]; }
        if (j == 0) accA += b2[obase + o];
        TAB[(size_t)(j * 257) * ODIM + obase + o] = make_float2(accA, accB);
#pragma unroll
        for (int g = 0; g < NGR; g++) {
            float ta = eta[g][o], tb = etb[g][o];
            eta[g][o] = accA; etb[g][o] = accB;
            accA += ta; accB += tb;
        }
    }
    __syncthreads();

    // ---- pass 2: recompute with offset, write rows r+1 ----
    {
        float ra = eta[rr][oc], rb = etb[rr][oc];
#pragma unroll
        for (int k = 0; k < CHK; k++) {
            int r = rr * CHK + k;
            float we = W2[hs_s[r] * ODIM + obase + oc];
            ra = fmaf(pe_s[r], we, ra);
            rb = fmaf(ke_s[r], we, rb);
            TAB[(size_t)(j * 257 + r + 1) * ODIM + obase + oc] = make_float2(ra, rb);
        }
    }
}

// ============ K2: per-sample lookup + combine ============
__global__ __launch_bounds__(256) void gnn_main(const float* __restrict__ latent,
                                                const float* __restrict__ ws,
                                                float* __restrict__ out) {
    const int t = threadIdx.x;
    const int bs = blockIdx.x * SPB;

    __shared__ float tau_s[NNODE][HDIM];   // 8 KiB
    __shared__ float A_s[64];
    __shared__ float lat_s[SPB][NNODE];
    __shared__ float cc_s[SPB][NNODE];
    __shared__ int   rr_s[SPB][NNODE];

    for (int k = t; k < NNODE * HDIM; k += 256)
        ((float*)tau_s)[k] = ws[OFF_TAU + k];
    if (t < 64) A_s[t] = ws[OFF_AHAT + t];
    if (t >= 128) {
        int u = t - 128;
        int s = u >> 3, qq = u & 7;
        lat_s[s][qq] = latent[(size_t)(bs + s) * FDIM + qq];
    }
    __syncthreads();

    if (t < SPB * NNODE) {   // 128 threads: (s, i)
        int s = t >> 3, i = t & 7;
        float mx = -1e30f;
#pragma unroll
        for (int qq = 0; qq < NNODE; qq++) mx = fmaxf(mx, lat_s[s][qq]);
        float sum = 0.f, acc = 0.f;
#pragma unroll
        for (int qq = 0; qq < NNODE; qq++) {
            float e = expf(lat_s[s][qq] - mx);
            sum += e;
            acc = fmaf(A_s[i * NNODE + qq], e, acc);
        }
        float c = acc / sum;
        cc_s[s][i] = c;
        int lo = 0, hi = HDIM;
        while (lo < hi) {
            int mid = (lo + hi) >> 1;
            if (tau_s[i][mid] < c) lo = mid + 1; else hi = mid;
        }
        rr_s[s][i] = lo;
    }
    __syncthreads();

    const int o = t & (ODIM - 1);
    const int sh = t >> 7;                 // 0 or 1
    const float2* TAB = (const float2*)(ws + OFF_TAB);

#pragma unroll 2
    for (int s = sh; s < SPB; s += 2) {
        float acc = 0.f;
#pragma unroll
        for (int jj = 0; jj < NNODE; jj++) {
            int r = rr_s[s][jj];
            float c = cc_s[s][jj];
            float2 ab = TAB[(size_t)(jj * 257 + r) * ODIM + o];
            acc += fmaf(c, ab.y, ab.x);
        }
        out[(size_t)(bs + s) * ODIM + o] = acc;
    }
}

extern "C" void kernel_launch(void* const* d_in, const int* in_sizes, int n_in,
                              void* d_out, int out_size, void* d_ws, size_t ws_size,
                              hipStream_t stream) {
    const float* latent = (const float*)d_in[0];
    const float* nf     = (const float*)d_in[1];
    const float* ea     = (const float*)d_in[2];
    const float* W1     = (const float*)d_in[3];
    const float* b1     = (const float*)d_in[4];
    const float* W2     = (const float*)d_in[5];
    const float* b2     = (const float*)d_in[6];
    float* out = (float*)d_out;
    float* ws  = (float*)d_ws;

    hipLaunchKernelGGL(gnn_build, dim3(NNODE * QCH), dim3(1024), 0, stream,
                       nf, W1, ea, b1, W2, b2, ws);
    hipLaunchKernelGGL(gnn_main, dim3(NBLK), dim3(256), 0, stream, latent, ws, out);
}